// Round 7
// baseline (102162.158 us; speedup 1.0000x reference)
//
#include <hip/hip_runtime.h>

#define HH 128      // hidden size
#define G4 512      // 4*HH gates
#define TT 102400   // sequence length
#define BB 8        // batch
#define XS 801      // x_lds per-batch stride (801%32=1 -> bank spread)
#define HS2 144     // hh2 per-batch stride in halfs

typedef _Float16 v2h __attribute__((ext_vector_type(2)));
typedef _Float16 v8h __attribute__((ext_vector_type(8)));
typedef float    f4v __attribute__((ext_vector_type(4)));

#define MFMA16(A, B, C) __builtin_amdgcn_mfma_f32_16x16x32_f16((A), (B), (C), 0, 0, 0)

#if __has_builtin(__builtin_amdgcn_fdot2)
#define FDOT2(a, b, c) __builtin_amdgcn_fdot2((a), (b), (c), false)
#else
static __device__ __forceinline__ float fdot2_fb(v2h a, v2h b, float c) {
    return fmaf((float)a[0], (float)b[0], fmaf((float)a[1], (float)b[1], c));
}
#define FDOT2(a, b, c) fdot2_fb((a), (b), (c))
#endif

template<int CTRL>
__device__ __forceinline__ float dpp_mov(float v) {
    return __int_as_float(
        __builtin_amdgcn_update_dpp(0, __float_as_int(v), CTRL, 0xF, 0xF, true));
}

__device__ __forceinline__ float tanh_f(float x) {
    return fmaf(2.0f, __builtin_amdgcn_rcpf(1.0f + __expf(-2.0f * x)), -1.0f);
}
__device__ __forceinline__ float sigm_f(float x) {
    return __builtin_amdgcn_rcpf(1.0f + __expf(-x));
}

union HI { int i; v2h h; };

// R7-verified reduce-to-distinct dot (stage B only).
__device__ __forceinline__ float dotred(const v2h w[8][8],
                                        const _Float16* __restrict__ hsl,
                                        bool bp1, bool bp2, bool bp3) {
    const int4* hp4 = (const int4*)hsl;
    int4 ha = hp4[0], hb = hp4[1];
    int hp[8] = {ha.x, ha.y, ha.z, ha.w, hb.x, hb.y, hb.z, hb.w};
    float acc[8];
#pragma unroll
    for (int r = 0; r < 8; ++r) acc[r] = 0.f;
#pragma unroll
    for (int i = 0; i < 8; ++i) {
        HI u; u.i = hp[i];
#pragma unroll
        for (int r = 0; r < 8; ++r) acc[r] = FDOT2(w[r][i], u.h, acc[r]);
    }
    float b0[4];
#pragma unroll
    for (int m = 0; m < 4; ++m) {
        float send = bp1 ? acc[2 * m] : acc[2 * m + 1];
        float keep = bp1 ? acc[2 * m + 1] : acc[2 * m];
        b0[m] = keep + dpp_mov<0xB1>(send);
    }
    float d0[2];
#pragma unroll
    for (int i = 0; i < 2; ++i) {
        float send = bp2 ? b0[i] : b0[i + 2];
        float keep = bp2 ? b0[i + 2] : b0[i];
        d0[i] = keep + dpp_mov<0x4E>(send);
    }
    float send = bp3 ? d0[0] : d0[1];
    float keep = bp3 ? d0[1] : d0[0];
    return keep + dpp_mov<0x141>(send);
}

// stage-B weight slices (512-thread blocks, Q=0..63)
__device__ __forceinline__ void load_w8h(const float* __restrict__ W,
                                         int Q, int j, v2h w[8][8]) {
#pragma unroll
    for (int r = 0; r < 8; ++r) {
        int row = 2 * Q + (r & 1) + 128 * (r >> 1);
        const float4* rp = (const float4*)(W + (size_t)row * HH + 16 * j);
#pragma unroll
        for (int i = 0; i < 4; ++i) {
            float4 f = rp[i];
            w[r][2 * i]     = (v2h){(_Float16)f.x, (_Float16)f.y};
            w[r][2 * i + 1] = (v2h){(_Float16)f.z, (_Float16)f.w};
        }
    }
}

// ---------------------------------------------------------------------------
// R16 (resubmit): batch-shared MFMA chains at 8 waves (2/SIMD). R15
// post-mortem: regression was VGPR spill (af=128 VGPR at 4 waves); per-CU
// MFMA work is structurally 128 tiles/step (B=8 < 16 cols => 2x col waste).
// Wave w owns cell rows [16w,16w+16) x 4 gates = 16 tiles -> af=64 VGPR,
// no spill. Cols carry batches (0-7; 8-15 mirror). Mirror lanes split the
// 4-row quad: rh=col>>3 owns r in {2rh,2rh+1} -> 2 cells/lane in the tail.
// Layouts (R14/R15 HW-verified): A row=l&15, k=32kt+8*(l>>4)+j; B col=l&15,
// same k map; D col=l&15, row=4*(l>>4)+reg.
// ---------------------------------------------------------------------------
__global__ void __launch_bounds__(512, 1)
lstm_slot_kernel(
    const float* __restrict__ x,
    const float* __restrict__ Wih0, const float* __restrict__ Whh0,
    const float* __restrict__ bih0, const float* __restrict__ bhh0,
    const float* __restrict__ Wih1, const float* __restrict__ Whh1,
    const float* __restrict__ bih1, const float* __restrict__ bhh1,
    float* __restrict__ h1s, float* __restrict__ c1s,
    float* __restrict__ h2s, float* __restrict__ c2s,
    double* __restrict__ pooled,
    _Float16* __restrict__ h1ring,  // [2][B][chunkT][HH]   fp16
    float* __restrict__ xpring,     // [2][B][chunkT][HH][4] (t,cell,gate) fp32
    int c, int chunkT, int nchunks)
{
    __shared__ __align__(16) _Float16 hh2[2][BB * HS2];
    __shared__ __align__(16) float x_lds[BB * XS];
    const int t = threadIdx.x;

    if (blockIdx.x < 2) {
        // =============== chain blocks (0: layer0, 1: layer1) ===============
        const bool isA = (blockIdx.x == 0);
        const int cc = isA ? c : (c - 2);
        if (cc < 0 || cc >= nchunks) return;

        const int l   = t & 63;
        const int w   = t >> 6;          // wave 0..7: cells [16w, 16w+16)
        const int lhi = l >> 4;          // 0..3
        const int col = l & 15;
        const int bb  = col & 7;         // batch
        const int rh  = col >> 3;        // owns rows {2rh, 2rh+1} of its quad
        const int cellq = 16 * w + 4 * lhi;
        const int c0    = cellq + 2 * rh;      // first owned cell

        // ---- A fragments af[g][kt] ----
        const float* Wc = isA ? Whh0 : Whh1;
        v8h af[4][4];
#pragma unroll
        for (int g = 0; g < 4; ++g)
#pragma unroll
            for (int kt = 0; kt < 4; ++kt) {
                const float* wr = Wc + (size_t)(16 * w + 128 * g + col) * HH
                                + 32 * kt + 8 * lhi;
                f4v fa = *(const f4v*)wr, fb = *(const f4v*)(wr + 4);
                v8h v;
                v[0] = (_Float16)fa[0]; v[1] = (_Float16)fa[1];
                v[2] = (_Float16)fa[2]; v[3] = (_Float16)fa[3];
                v[4] = (_Float16)fb[0]; v[5] = (_Float16)fb[1];
                v[6] = (_Float16)fb[2]; v[7] = (_Float16)fb[3];
                af[g][kt] = v;
            }

        // bias folded into MFMA C-in (layer0; layer1 bias lives inside xp)
        f4v cin[4];
#pragma unroll
        for (int g = 0; g < 4; ++g) cin[g] = (f4v){0.f, 0.f, 0.f, 0.f};
        float wihv[2][4];
#pragma unroll
        for (int r2 = 0; r2 < 2; ++r2)
#pragma unroll
            for (int g = 0; g < 4; ++g) wihv[r2][g] = 0.f;
        if (isA) {
#pragma unroll
            for (int g = 0; g < 4; ++g)
#pragma unroll
                for (int r = 0; r < 4; ++r) {
                    int row = cellq + r + 128 * g;
                    cin[g][r] = bih0[row] + bhh0[row];
                }
#pragma unroll
            for (int r2 = 0; r2 < 2; ++r2)
#pragma unroll
                for (int g = 0; g < 4; ++g)
                    wihv[r2][g] = Wih0[c0 + r2 + 128 * g];
        }

        float* hst = isA ? h1s : h2s;
        float* cst = isA ? c1s : c2s;
        float cr0 = cst[bb * HH + c0];
        float cr1 = cst[bb * HH + c0 + 1];
        float hl0 = 0.f, hl1 = 0.f;
        float pac0 = 0.f, pac1 = 0.f;

        // stage h into hh2[0]
        for (int i = t; i < BB * HH; i += 512)
            hh2[0][(i >> 7) * HS2 + (i & 127)] = (_Float16)hst[i];
        // stage this chunk's x (layer0)
        if (isA) {
            for (int b_ = 0; b_ < 8; ++b_)
                for (int tp = t; tp < chunkT; tp += 512)
                    x_lds[b_ * XS + tp] = x[(size_t)b_ * TT + (size_t)cc * chunkT + tp];
        }

        _Float16* rp = h1ring + ((size_t)((c & 1) * BB + bb)) * (size_t)chunkT * HH + c0;
        const float* xps = xpring
            + ((size_t)((cc & 1) * BB + bb)) * (size_t)chunkT * G4 + 4 * c0;

        f4v xc0 = {0,0,0,0}, xc1 = {0,0,0,0};
        f4v xn0 = {0,0,0,0}, xn1 = {0,0,0,0};
        if (!isA) {
            xc0 = *(const f4v*)(xps);
            xc1 = *(const f4v*)(xps + 4);
        }
        __syncthreads();

#define CSTEP(PB, S, SN, XA0, XA1, XB0, XB1) do {                             \
        if (!isA && (SN) < chunkT) {                                          \
            const float* q_ = xps + (size_t)(SN) * G4;                        \
            XB0 = *(const f4v*)q_;  XB1 = *(const f4v*)(q_ + 4);              \
        }                                                                     \
        const _Float16* hb_ = &hh2[PB][bb * HS2 + 8 * lhi];                   \
        v8h B0_ = *(const v8h*)(hb_);                                         \
        v8h B1_ = *(const v8h*)(hb_ + 32);                                    \
        v8h B2_ = *(const v8h*)(hb_ + 64);                                    \
        v8h B3_ = *(const v8h*)(hb_ + 96);                                    \
        f4v a0_ = cin[0], a1_ = cin[1], a2_ = cin[2], a3_ = cin[3];           \
        a0_ = MFMA16(af[0][0], B0_, a0_);                                     \
        a1_ = MFMA16(af[1][0], B0_, a1_);                                     \
        a2_ = MFMA16(af[2][0], B0_, a2_);                                     \
        a3_ = MFMA16(af[3][0], B0_, a3_);                                     \
        a0_ = MFMA16(af[0][1], B1_, a0_);                                     \
        a1_ = MFMA16(af[1][1], B1_, a1_);                                     \
        a2_ = MFMA16(af[2][1], B1_, a2_);                                     \
        a3_ = MFMA16(af[3][1], B1_, a3_);                                     \
        a0_ = MFMA16(af[0][2], B2_, a0_);                                     \
        a1_ = MFMA16(af[1][2], B2_, a1_);                                     \
        a2_ = MFMA16(af[2][2], B2_, a2_);                                     \
        a3_ = MFMA16(af[3][2], B2_, a3_);                                     \
        a0_ = MFMA16(af[0][3], B3_, a0_);                                     \
        a1_ = MFMA16(af[1][3], B3_, a1_);                                     \
        a2_ = MFMA16(af[2][3], B3_, a2_);                                     \
        a3_ = MFMA16(af[3][3], B3_, a3_);                                     \
        float xt_ = x_lds[bb * XS + (S)];                                     \
        float h0_, h1_;                                                       \
        {                                                                     \
            const int r_ = 2 * rh;                                            \
            float pi_, pf_, pg_, po_;                                         \
            if (isA) { pi_ = fmaf(xt_, wihv[0][0], a0_[r_]);                  \
                       pf_ = fmaf(xt_, wihv[0][1], a1_[r_]);                  \
                       pg_ = fmaf(xt_, wihv[0][2], a2_[r_]);                  \
                       po_ = fmaf(xt_, wihv[0][3], a3_[r_]); }                \
            else { pi_ = a0_[r_] + XA0[0]; pf_ = a1_[r_] + XA0[1];            \
                   pg_ = a2_[r_] + XA0[2]; po_ = a3_[r_] + XA0[3]; }          \
            float gi_ = sigm_f(pi_), gf_ = sigm_f(pf_);                       \
            float gg_ = tanh_f(pg_), go_ = sigm_f(po_);                       \
            cr0 = fmaf(gf_, cr0, gi_ * gg_);  h0_ = go_ * tanh_f(cr0);        \
        }                                                                     \
        {                                                                     \
            const int r_ = 2 * rh + 1;                                        \
            float pi_, pf_, pg_, po_;                                         \
            if (isA) { pi_ = fmaf(xt_, wihv[1][0], a0_[r_]);                  \
                       pf_ = fmaf(xt_, wihv[1][1], a1_[r_]);                  \
                       pg_ = fmaf(xt_, wihv[1][2], a2_[r_]);                  \
                       po_ = fmaf(xt_, wihv[1][3], a3_[r_]); }                \
            else { pi_ = a0_[r_] + XA1[0]; pf_ = a1_[r_] + XA1[1];            \
                   pg_ = a2_[r_] + XA1[2]; po_ = a3_[r_] + XA1[3]; }          \
            float gi_ = sigm_f(pi_), gf_ = sigm_f(pf_);                       \
            float gg_ = tanh_f(pg_), go_ = sigm_f(po_);                       \
            cr1 = fmaf(gf_, cr1, gi_ * gg_);  h1_ = go_ * tanh_f(cr1);        \
        }                                                                     \
        v2h pk_ = (v2h){(_Float16)h0_, (_Float16)h1_};                        \
        *(v2h*)(&hh2[(PB) ^ 1][bb * HS2 + c0]) = pk_;                         \
        if (isA) *(v2h*)(rp + (size_t)(S) * HH) = pk_;                        \
        else { pac0 += h0_; pac1 += h1_; }                                    \
        hl0 = h0_; hl1 = h1_;                                                 \
        __syncthreads();                                                      \
    } while (0)

        for (int s = 0; s < chunkT; s += 2) {
            CSTEP(0, s,     s + 1, xc0, xc1, xn0, xn1);
            CSTEP(1, s + 1, s + 2, xn0, xn1, xc0, xc1);
        }
#undef CSTEP

        cst[bb * HH + c0]     = cr0;
        cst[bb * HH + c0 + 1] = cr1;
        hst[bb * HH + c0]     = hl0;
        hst[bb * HH + c0 + 1] = hl1;
        if (!isA) {
            pooled[bb * HH + c0]     += (double)pac0;
            pooled[bb * HH + c0 + 1] += (double)pac1;
        }

    } else {
        // ---------------- stage B: xp1 = Wih1 @ h1 + bias, chunk c-1 -------
        const int bc = c - 1;
        if (bc < 0 || bc >= nchunks) return;
        const int Q = t >> 3;                 // 0..63
        const int j = t & 7;
        const bool bp1 = ((j ^ (j >> 2)) & 1) != 0;
        const bool bp2 = ((j ^ (j >> 1)) & 1) != 0;
        const bool bp3 = ((j >> 2) & 1) != 0;
        const int cellj = bp1 ? 1 : 0;
        const int gatej = (bp2 ? 2 : 0) + (bp3 ? 1 : 0);
        const int myc   = 2 * Q + cellj;
        const int myrow = myc + 128 * gatej;

        const int ib = blockIdx.x - 2;        // 0..63
        const int bb2 = ib >> 3;              // batch
        const int sl = ib & 7;                // t-slice (stride 8)
        v2h wB[8][8];
        load_w8h(Wih1, Q, j, wB);
        const float bias_l = bih1[myrow] + bhh1[myrow];
        const _Float16* hrp = h1ring
            + ((size_t)((bc & 1) * BB + bb2)) * (size_t)chunkT * HH;
        float* xpw = xpring + ((size_t)((bc & 1) * BB + bb2)) * (size_t)chunkT * G4;
        _Float16* hhB = &hh2[0][0];           // 256 halfs, reuses chain LDS
        if (t < HH) hhB[t] = hrp[(size_t)sl * HH + t];
        __syncthreads();
        int pb = 0;
        for (int tt = sl; tt < chunkT; tt += 8) {
            int ttn = tt + 8;
            bool pf = (t < HH) && (ttn < chunkT);
            _Float16 hn = (_Float16)0.f;
            if (pf) hn = hrp[(size_t)ttn * HH + t];
            float sfin = dotred(wB, hhB + pb * HH + 16 * j, bp1, bp2, bp3);
            if (pf) hhB[(pb ^ 1) * HH + t] = hn;
            xpw[(size_t)tt * G4 + 4 * myc + gatej] = sfin + bias_l;
            __syncthreads();
            pb ^= 1;
        }
    }
}

// ---------------- head: mean-pool (done) -> FC+ReLU -> FC ------------------
__global__ void head_kernel(const double* __restrict__ pooled,
                            const float* __restrict__ fcW1, const float* __restrict__ fcb1,
                            const float* __restrict__ fcW2, const float* __restrict__ fcb2,
                            float* __restrict__ out)
{
    __shared__ float p_s[HH];
    __shared__ float hid_s[64];
    const int b = blockIdx.x, t = threadIdx.x;
    if (t < HH) p_s[t] = (float)(pooled[b * HH + t] * (1.0 / (double)TT));
    __syncthreads();
    if (t < 64) {
        float acc = fcb1[t];
#pragma unroll 8
        for (int k = 0; k < HH; ++k) acc = fmaf(p_s[k], fcW1[t * HH + k], acc);
        hid_s[t] = fmaxf(acc, 0.f);
    }
    __syncthreads();
    if (t < 11) {
        float acc = fcb2[t];
#pragma unroll
        for (int k = 0; k < 64; ++k) acc = fmaf(hid_s[k], fcW2[t * 64 + k], acc);
        out[b * 11 + t] = acc;
    }
}

// ---------------------------------------------------------------------------
extern "C" void kernel_launch(void* const* d_in, const int* in_sizes, int n_in,
                              void* d_out, int out_size, void* d_ws, size_t ws_size,
                              hipStream_t stream)
{
    const float* x    = (const float*)d_in[0];
    const float* Wih0 = (const float*)d_in[1];
    const float* Whh0 = (const float*)d_in[2];
    const float* bih0 = (const float*)d_in[3];
    const float* bhh0 = (const float*)d_in[4];
    const float* Wih1 = (const float*)d_in[5];
    const float* Whh1 = (const float*)d_in[6];
    const float* bih1 = (const float*)d_in[7];
    const float* bhh1 = (const float*)d_in[8];
    const float* fcW1 = (const float*)d_in[9];
    const float* fcb1 = (const float*)d_in[10];
    const float* fcW2 = (const float*)d_in[11];
    const float* fcb2 = (const float*)d_in[12];
    float* out = (float*)d_out;

    // ---- workspace layout ----
    char* wsp = (char*)d_ws;
    float*  h1s    = (float*) (wsp + 0);
    float*  c1s    = (float*) (wsp + 4096);
    float*  h2s    = (float*) (wsp + 8192);
    float*  c2s    = (float*) (wsp + 12288);
    double* pooled = (double*)(wsp + 16384);          // 8 KB
    const size_t STATE_BYTES = 24576;

    // per-t ring bytes: h1 fp16 4096 + xp fp32 32768 = 36864
    static const int cands[] = {800, 400, 160, 80, 40, 8};
    int chunkT = 8;
    for (int i = 0; i < 6; ++i) {
        size_t need = STATE_BYTES + (size_t)36864 * (size_t)cands[i];
        if (need <= ws_size) { chunkT = cands[i]; break; }
    }
    const int nchunks = TT / chunkT;

    _Float16* h1ring = (_Float16*)(wsp + STATE_BYTES);
    float* xpring = (float*)(wsp + STATE_BYTES + (size_t)2 * BB * chunkT * HH * 2);

    // zero persistent state (h/c/pooled); ws is re-poisoned before every call
    hipMemsetAsync(d_ws, 0, STATE_BYTES, stream);

    // pipeline: slot c runs A(c) || B(c-1) || C(c-2)
    const int nslots = nchunks + 2;
    for (int c = 0; c < nslots; ++c) {
        lstm_slot_kernel<<<66, 512, 0, stream>>>(
            x, Wih0, Whh0, bih0, bhh0, Wih1, Whh1, bih1, bhh1,
            h1s, c1s, h2s, c2s, pooled, h1ring, xpring,
            c, chunkT, nchunks);
    }
    head_kernel<<<BB, 128, 0, stream>>>(pooled, fcW1, fcb1, fcW2, fcb2, out);
}

// Round 8
// 57930.457 us; speedup vs baseline: 1.7635x; 1.7635x over previous
//
#include <hip/hip_runtime.h>

#define HH 128      // hidden size
#define G4 512      // 4*HH gates
#define TT 102400   // sequence length
#define BB 8        // batch

typedef _Float16 v2h __attribute__((ext_vector_type(2)));

#if __has_builtin(__builtin_amdgcn_fdot2)
#define FDOT2(a, b, c) __builtin_amdgcn_fdot2((a), (b), (c), false)
#else
static __device__ __forceinline__ float fdot2_fb(v2h a, v2h b, float c) {
    return fmaf((float)a[0], (float)b[0], fmaf((float)a[1], (float)b[1], c));
}
#define FDOT2(a, b, c) fdot2_fb((a), (b), (c))
#endif

// DPP lane move (VALU pipe): 0xB1=xor1(quad), 0x4E=xor2(quad), 0x141=xor7(row-half mirror)
template<int CTRL>
__device__ __forceinline__ float dpp_mov(float v) {
    return __int_as_float(
        __builtin_amdgcn_update_dpp(0, __float_as_int(v), CTRL, 0xF, 0xF, true));
}

__device__ __forceinline__ float tanh_f(float x) {
    return fmaf(2.0f, __builtin_amdgcn_rcpf(1.0f + __expf(-2.0f * x)), -1.0f);
}

// R12 light barrier — LDS-visibility only (lgkmcnt, no vmcnt drain).
// Global ring/xp stores are consumed only by the NEXT kernel launch.
static __device__ __forceinline__ void bar_lds() {
    __builtin_amdgcn_sched_barrier(0);
    asm volatile("s_waitcnt lgkmcnt(0)" ::: "memory");
    __builtin_amdgcn_s_barrier();
    __builtin_amdgcn_sched_barrier(0);
}

union HI { int i; v2h h; };

// ---------------------------------------------------------------------------
// R7-verified reduce-to-distinct: lane j of each 8-lane group covers
// k in [16j,16j+16) of 8 gate rows (rho: bit0=cell, bits2:1=gate).
// Keep-functionals (GF(2)): phi1=j0^j2 (mask1), phi2=j0^j1 (mask2), phi3=j2
// (mask7). Lane j ends with the FULL 128-dot of row
// (cell=j0^j2, gate=2*(j0^j1)+j2). cell0 {i@0,f@7,g@2,o@5}, cell1 {i@3,f@4,g@1,o@6}.
// ---------------------------------------------------------------------------
__device__ __forceinline__ float dotred(const v2h w[8][8],
                                        const _Float16* __restrict__ hsl,
                                        bool bp1, bool bp2, bool bp3) {
    const int4* hp4 = (const int4*)hsl;     // 2x ds_read_b128 (16 halfs)
    int4 ha = hp4[0], hb = hp4[1];
    int hp[8] = {ha.x, ha.y, ha.z, ha.w, hb.x, hb.y, hb.z, hb.w};
    float acc[8];
#pragma unroll
    for (int r = 0; r < 8; ++r) acc[r] = 0.f;
#pragma unroll
    for (int i = 0; i < 8; ++i) {
        HI u; u.i = hp[i];
#pragma unroll
        for (int r = 0; r < 8; ++r) acc[r] = FDOT2(w[r][i], u.h, acc[r]);
    }
    // round 1 (mask 1): reduce cell bit; keep rho0 == bp1
    float b0[4];
#pragma unroll
    for (int m = 0; m < 4; ++m) {
        float send = bp1 ? acc[2 * m] : acc[2 * m + 1];
        float keep = bp1 ? acc[2 * m + 1] : acc[2 * m];
        b0[m] = keep + dpp_mov<0xB1>(send);
    }
    // round 2 (mask 2): reduce gate-hi bit; keep g1 == bp2 (= j0^j1)
    float d0[2];
#pragma unroll
    for (int i = 0; i < 2; ++i) {
        float send = bp2 ? b0[i] : b0[i + 2];
        float keep = bp2 ? b0[i + 2] : b0[i];
        d0[i] = keep + dpp_mov<0x4E>(send);
    }
    // round 3 (mask 7): reduce gate-lo bit; keep g0 == bp3 (= j2)
    float send = bp3 ? d0[0] : d0[1];
    float keep = bp3 ? d0[1] : d0[0];
    return keep + dpp_mov<0x141>(send);
}

// load this lane's fp16 weight slices: rows rho=0..7 -> W row 2Q+(rho&1)+128*(rho>>1)
__device__ __forceinline__ void load_w8h(const float* __restrict__ W,
                                         int Q, int j, v2h w[8][8]) {
#pragma unroll
    for (int r = 0; r < 8; ++r) {
        int row = 2 * Q + (r & 1) + 128 * (r >> 1);
        const float4* rp = (const float4*)(W + (size_t)row * HH + 16 * j);
#pragma unroll
        for (int i = 0; i < 4; ++i) {
            float4 f = rp[i];
            w[r][2 * i]     = (v2h){(_Float16)f.x, (_Float16)f.y};
            w[r][2 * i + 1] = (v2h){(_Float16)f.z, (_Float16)f.w};
        }
    }
}

// ---------------------------------------------------------------------------
// One pipeline slot (512 threads/block) — R7/R11-verified structure:
//   blocks 0..7  = stage A (layer0 chain, chunk c)
//   blocks 8..15 = stage C (layer1 chain, chunk c-2)
//   blocks 16..79= stage B (xp1 GEMM, chunk c-1): 8 batch x 8 t-slice
// Stages independent within a launch; stream order gives producer->consumer
// ordering across launches. Chain CUs are VALU-issue-bound (R10 diagnostic);
// R12 removes the per-step vmcnt(0) drain from the chain critical path.
// R13-R16 post-mortems: MFMA reformulations (broadcast 572ns, batched 982ns)
// do not beat this 557ns/step — the bound is the sequential recurrence
// (104000 steps x issue+exchange+barrier floor), not any pipe.
// ---------------------------------------------------------------------------
__global__ void __launch_bounds__(512, 2)
lstm_slot_kernel(
    const float* __restrict__ x,
    const float* __restrict__ Wih0, const float* __restrict__ Whh0,
    const float* __restrict__ bih0, const float* __restrict__ bhh0,
    const float* __restrict__ Wih1, const float* __restrict__ Whh1,
    const float* __restrict__ bih1, const float* __restrict__ bhh1,
    float* __restrict__ h1s, float* __restrict__ c1s,
    float* __restrict__ h2s, float* __restrict__ c2s,
    double* __restrict__ pooled,
    _Float16* __restrict__ h1ring,  // [2][B][chunkT][HH]   fp16
    float* __restrict__ xpring,     // [2][B][chunkT][HH][4] (t,cell,gate) fp32
    int c, int chunkT, int nchunks)
{
    __shared__ __align__(32) _Float16 hh[2 * HH];
    const int t = threadIdx.x;
    const int Q = t >> 3;                 // 8-lane group -> cells {2Q, 2Q+1}
    const int j = t & 7;
    const bool bp1 = ((j ^ (j >> 2)) & 1) != 0;   // phi1 = j0^j2 (cell bit)
    const bool bp2 = ((j ^ (j >> 1)) & 1) != 0;   // phi2 = j0^j1 (gate hi)
    const bool bp3 = ((j >> 2) & 1) != 0;         // phi3 = j2    (gate lo)
    const int cellj = bp1 ? 1 : 0;
    const int gatej = (bp2 ? 2 : 0) + (bp3 ? 1 : 0);
    const int myc   = 2 * Q + cellj;
    const int myrow = myc + 128 * gatej;
    const bool owner = (gatej == 0);              // gate-i lanes: j in {0,3}
    // branchless activation constants: sigmoid for i,f,o; tanh for g(=gate2)
    const bool isg = (gatej == 2);
    const float fe = isg ? -2.f : -1.f;
    const float fm = isg ?  2.f :  1.f;
    const float fa = isg ? -1.f :  0.f;

    if (blockIdx.x < 16) {
        // =============== chain stages (A: layer0, C: layer1) ===============
        const bool isA = (blockIdx.x < 8);
        const int cc = isA ? c : (c - 2);
        if (cc < 0 || cc >= nchunks) return;
        const int b = blockIdx.x & 7;

        v2h w[8][8];
        load_w8h(isA ? Whh0 : Whh1, Q, j, w);
        float bias_l = 0.f, wih_l = 0.f;
        if (isA) { bias_l = bih0[myrow] + bhh0[myrow]; wih_l = Wih0[myrow]; }

        float* hst = isA ? h1s : h2s;
        float* cst = isA ? c1s : c2s;
        float c_reg = cst[b * HH + myc];
        if (t < HH) hh[t] = (_Float16)hst[b * HH + t];

        _Float16* ringp = h1ring + ((size_t)((c & 1) * BB + b)) * (size_t)chunkT * HH;
        const float4* xb4 = (const float4*)(x + (size_t)b * TT + (size_t)cc * chunkT);
        const float* xps = xpring
            + ((size_t)((cc & 1) * BB + b)) * (size_t)chunkT * G4 + 4 * myc + gatej;

        const int nt4 = chunkT >> 2;
        float4 xq = {0, 0, 0, 0};
        float xpc[4] = {0, 0, 0, 0};
        if (isA) xq = xb4[0];
        else {
#pragma unroll
            for (int u = 0; u < 4; ++u) xpc[u] = xps[(size_t)u * G4];
        }
        double pacc = 0.0;
        float hfin = 0.f;
        bar_lds();

        for (int t4 = 0; t4 < nt4; ++t4) {
            float4 xqn = {0, 0, 0, 0};
            float xpn[4] = {0, 0, 0, 0};
            if (isA) {
                if (t4 + 1 < nt4) xqn = xb4[t4 + 1];
            } else if (t4 + 1 < nt4) {
#pragma unroll
                for (int u = 0; u < 4; ++u)
                    xpn[u] = xps[(size_t)(t4 * 4 + 4 + u) * G4];
            }
#pragma unroll
            for (int u = 0; u < 4; ++u) {
                const int buf = u & 1;                 // static step parity
                float sfin = dotred(w, hh + buf * HH + 16 * j, bp1, bp2, bp3);
                float pre;
                if (isA) {
                    float xt = (u == 0) ? xq.x : (u == 1) ? xq.y
                             : (u == 2) ? xq.z : xq.w;
                    pre = fmaf(xt, wih_l, sfin + bias_l);
                } else {
                    pre = sfin + xpc[u];
                }
                // one activation per lane (its own gate)
                float e  = __expf(pre * fe);
                float rr = __builtin_amdgcn_rcpf(1.0f + e);
                float act = fmaf(fm, rr, fa);
                // gate-gather at owners (gate i): f@j^7, g@j^2, o@j^5
                float t1 = dpp_mov<0x141>(act);   // act[j^7] = f
                float t2 = dpp_mov<0x4E>(act);    // act[j^2] = g
                float t3 = dpp_mov<0x4E>(t1);     // act[j^5] = o
                c_reg = fmaf(t1, c_reg, act * t2);   // c = f*c + i*g
                float th = tanh_f(c_reg);
                float hv = t3 * th;                  // h = o*tanh(c)
                hfin = hv;
                if (owner) {
                    hh[(buf ^ 1) * HH + myc] = (_Float16)hv;
                    if (isA) ringp[(size_t)(t4 * 4 + u) * HH + myc] = (_Float16)hv;
                    else     pacc += (double)hv;
                }
                bar_lds();
            }
            xq = xqn;
            if (!isA) {
#pragma unroll
                for (int u = 0; u < 4; ++u) xpc[u] = xpn[u];
            }
        }
        if (owner) {
            cst[b * HH + myc] = c_reg;
            hst[b * HH + myc] = hfin;
            if (!isA) pooled[b * HH + myc] += pacc;
        }

    } else {
        // ---------------- stage B: xp1 = Wih1 @ h1 + bias, chunk c-1 -------
        const int bc = c - 1;
        if (bc < 0 || bc >= nchunks) return;
        const int ib = blockIdx.x - 16;       // 0..63
        const int bb = ib >> 3;               // batch
        const int sl = ib & 7;                // t-slice (stride 8)
        v2h w[8][8];
        load_w8h(Wih1, Q, j, w);
        const float bias_l = bih1[myrow] + bhh1[myrow];
        const _Float16* hrp = h1ring
            + ((size_t)((bc & 1) * BB + bb)) * (size_t)chunkT * HH;
        float* xpw = xpring + ((size_t)((bc & 1) * BB + bb)) * (size_t)chunkT * G4;
        if (t < HH) hh[t] = hrp[(size_t)sl * HH + t];
        bar_lds();
        int pb = 0;
        for (int tt = sl; tt < chunkT; tt += 8) {
            int ttn = tt + 8;
            bool pf = (t < HH) && (ttn < chunkT);
            _Float16 hn = (_Float16)0.f;
            if (pf) hn = hrp[(size_t)ttn * HH + t];          // prefetch
            float sfin = dotred(w, hh + pb * HH + 16 * j, bp1, bp2, bp3);
            if (pf) hh[(pb ^ 1) * HH + t] = hn;
            xpw[(size_t)tt * G4 + 4 * myc + gatej] = sfin + bias_l;
            bar_lds();
            pb ^= 1;
        }
    }
}

// ---------------- head: mean-pool (done) -> FC+ReLU -> FC ------------------
__global__ void head_kernel(const double* __restrict__ pooled,
                            const float* __restrict__ fcW1, const float* __restrict__ fcb1,
                            const float* __restrict__ fcW2, const float* __restrict__ fcb2,
                            float* __restrict__ out)
{
    __shared__ float p_s[HH];
    __shared__ float hid_s[64];
    const int b = blockIdx.x, t = threadIdx.x;
    if (t < HH) p_s[t] = (float)(pooled[b * HH + t] * (1.0 / (double)TT));
    __syncthreads();
    if (t < 64) {
        float acc = fcb1[t];
#pragma unroll 8
        for (int k = 0; k < HH; ++k) acc = fmaf(p_s[k], fcW1[t * HH + k], acc);
        hid_s[t] = fmaxf(acc, 0.f);
    }
    __syncthreads();
    if (t < 11) {
        float acc = fcb2[t];
#pragma unroll
        for (int k = 0; k < 64; ++k) acc = fmaf(hid_s[k], fcW2[t * 64 + k], acc);
        out[b * 11 + t] = acc;
    }
}

// ---------------------------------------------------------------------------
extern "C" void kernel_launch(void* const* d_in, const int* in_sizes, int n_in,
                              void* d_out, int out_size, void* d_ws, size_t ws_size,
                              hipStream_t stream)
{
    const float* x    = (const float*)d_in[0];
    const float* Wih0 = (const float*)d_in[1];
    const float* Whh0 = (const float*)d_in[2];
    const float* bih0 = (const float*)d_in[3];
    const float* bhh0 = (const float*)d_in[4];
    const float* Wih1 = (const float*)d_in[5];
    const float* Whh1 = (const float*)d_in[6];
    const float* bih1 = (const float*)d_in[7];
    const float* bhh1 = (const float*)d_in[8];
    const float* fcW1 = (const float*)d_in[9];
    const float* fcb1 = (const float*)d_in[10];
    const float* fcW2 = (const float*)d_in[11];
    const float* fcb2 = (const float*)d_in[12];
    float* out = (float*)d_out;

    // ---- workspace layout ----
    char* wsp = (char*)d_ws;
    float*  h1s    = (float*) (wsp + 0);
    float*  c1s    = (float*) (wsp + 4096);
    float*  h2s    = (float*) (wsp + 8192);
    float*  c2s    = (float*) (wsp + 12288);
    double* pooled = (double*)(wsp + 16384);          // 8 KB
    const size_t STATE_BYTES = 24576;

    // per-t ring bytes: h1 fp16 4096 + xp fp32 32768 = 36864
    static const int cands[] = {800, 400, 160, 80, 40, 8};
    int chunkT = 8;
    for (int i = 0; i < 6; ++i) {
        size_t need = STATE_BYTES + (size_t)36864 * (size_t)cands[i];
        if (need <= ws_size) { chunkT = cands[i]; break; }
    }
    const int nchunks = TT / chunkT;

    _Float16* h1ring = (_Float16*)(wsp + STATE_BYTES);
    float* xpring = (float*)(wsp + STATE_BYTES + (size_t)2 * BB * chunkT * HH * 2);

    // zero persistent state (h/c/pooled); ws is re-poisoned before every call
    hipMemsetAsync(d_ws, 0, STATE_BYTES, stream);

    // pipeline: slot c runs A(c) || B(c-1) || C(c-2)
    const int nslots = nchunks + 2;
    for (int c = 0; c < nslots; ++c) {
        lstm_slot_kernel<<<80, 512, 0, stream>>>(
            x, Wih0, Whh0, bih0, bhh0, Wih1, Whh1, bih1, bhh1,
            h1s, c1s, h2s, c2s, pooled, h1ring, xpring,
            c, chunkT, nchunks);
    }
    head_kernel<<<BB, 128, 0, stream>>>(pooled, fcW1, fcb1, fcW2, fcb2, out);
}